// Round 1
// baseline (113.078 us; speedup 1.0000x reference)
//
#include <hip/hip_runtime.h>

// GraphAdjacencyLayer: W[i][j] = thresh((fn_i . fn_j)^2), fn = row-normalized features.
// N x 128 fp32 in, N x N fp32 out (N=8192).
//
// Strategy: bf16 MFMA Gram with fp32 per-row scales applied in the epilogue.
//   gram_norm[i][j] = (a_i . a_j)_bf16 * s_i * s_j, s = 1/(||a||_f32 + eps)
// K=128 fits in one LDS tile -> no K loop. Output writes (256 MB) are the roofline.

typedef __bf16 bf16x8 __attribute__((ext_vector_type(8)));
typedef float f32x4 __attribute__((ext_vector_type(4)));

__global__ __launch_bounds__(256, 2)
void gram_adj_kernel(const float* __restrict__ F, float* __restrict__ out, int N)
{
    // bf16 tiles, XOR-swizzled to kill the stride-256B ds_read_b128 bank conflict (T2)
    __shared__ __align__(16) unsigned short Abf[128 * 128]; // 32 KB
    __shared__ __align__(16) unsigned short Bbf[128 * 128]; // 32 KB
    __shared__ float scA[128];
    __shared__ float scB[128];

    const int tid  = threadIdx.x;
    const int lane = tid & 63;
    const int wid  = tid >> 6;
    const int wm   = wid >> 1;      // wave row 0..1
    const int wn   = wid & 1;       // wave col 0..1
    const int br   = blockIdx.y;
    const int bc   = blockIdx.x;
    const int rowTileBase = br * 128;
    const int colTileBase = bc * 128;

    const float4* __restrict__ F4 = (const float4*)F;

    // ---------------- staging: fp32 -> bf16 LDS + row norms (single pass) -------------
    {
        const int c  = tid & 31;    // float4 column: covers k = 4c..4c+3
        const int r0 = tid >> 5;    // 0..7
        #pragma unroll 4
        for (int it = 0; it < 16; ++it) {
            const int r = it * 8 + r0;
            float4 va = F4[(size_t)(rowTileBase + r) * 32 + c];
            float4 vb = F4[(size_t)(colTileBase + r) * 32 + c];
            float ssa = va.x * va.x + va.y * va.y + va.z * va.z + va.w * va.w;
            float ssb = vb.x * vb.x + vb.y * vb.y + vb.z * vb.z + vb.w * vb.w;
            // reduce across the 32 lanes holding this row (xor masks stay in 32-group)
            #pragma unroll
            for (int m = 1; m <= 16; m <<= 1) {
                ssa += __shfl_xor(ssa, m, 64);
                ssb += __shfl_xor(ssb, m, 64);
            }
            if (c == 0) {
                scA[r] = 1.0f / (sqrtf(ssa) + 1e-12f);
                scB[r] = 1.0f / (sqrtf(ssb) + 1e-12f);
            }
            ushort4 ua, ub;
            ua.x = __builtin_bit_cast(unsigned short, (__bf16)va.x);
            ua.y = __builtin_bit_cast(unsigned short, (__bf16)va.y);
            ua.z = __builtin_bit_cast(unsigned short, (__bf16)va.z);
            ua.w = __builtin_bit_cast(unsigned short, (__bf16)va.w);
            ub.x = __builtin_bit_cast(unsigned short, (__bf16)vb.x);
            ub.y = __builtin_bit_cast(unsigned short, (__bf16)vb.y);
            ub.z = __builtin_bit_cast(unsigned short, (__bf16)vb.z);
            ub.w = __builtin_bit_cast(unsigned short, (__bf16)vb.w);
            const unsigned byte = (unsigned)r * 256u + (unsigned)c * 8u;
            const unsigned swz  = byte ^ ((unsigned)(r & 7) << 4);
            *(ushort4*)((char*)Abf + swz) = ua;
            *(ushort4*)((char*)Bbf + swz) = ub;
        }
    }
    __syncthreads();

    // ---------------- MFMA main: C_tile = A_tile * B_tile^T, K = 128 ------------------
    f32x4 acc[4][4];
    #pragma unroll
    for (int m = 0; m < 4; ++m)
        #pragma unroll
        for (int n = 0; n < 4; ++n)
            acc[m][n] = (f32x4){0.f, 0.f, 0.f, 0.f};

    const int fr  = lane & 15;   // fragment row (within 16)
    const int fkq = lane >> 4;   // k-quad 0..3

    #pragma unroll
    for (int ks = 0; ks < 4; ++ks) {
        bf16x8 a[4], b[4];
        #pragma unroll
        for (int m = 0; m < 4; ++m) {
            const int row = wm * 64 + m * 16 + fr;
            const unsigned byte = (unsigned)row * 256u + (unsigned)(ks * 64 + fkq * 16);
            const unsigned swz  = byte ^ ((unsigned)(row & 7) << 4);
            a[m] = *(const bf16x8*)((const char*)Abf + swz);
        }
        #pragma unroll
        for (int n = 0; n < 4; ++n) {
            const int row = wn * 64 + n * 16 + fr;
            const unsigned byte = (unsigned)row * 256u + (unsigned)(ks * 64 + fkq * 16);
            const unsigned swz  = byte ^ ((unsigned)(row & 7) << 4);
            b[n] = *(const bf16x8*)((const char*)Bbf + swz);
        }
        #pragma unroll
        for (int m = 0; m < 4; ++m)
            #pragma unroll
            for (int n = 0; n < 4; ++n)
                acc[m][n] = __builtin_amdgcn_mfma_f32_16x16x32_bf16(a[m], b[n], acc[m][n], 0, 0, 0);
    }

    // ---------------- epilogue: scale, square, threshold, zero-diag, store ------------
    float sB_[4];
    #pragma unroll
    for (int n = 0; n < 4; ++n) sB_[n] = scB[wn * 64 + n * 16 + fr];
    float sA_[16];
    #pragma unroll
    for (int m = 0; m < 4; ++m)
        #pragma unroll
        for (int j = 0; j < 4; ++j)
            sA_[m * 4 + j] = scA[wm * 64 + m * 16 + fkq * 4 + j];

    const int gcolBase = colTileBase + wn * 64 + fr;
    const int growBase = rowTileBase + wm * 64 + fkq * 4;

    #pragma unroll
    for (int m = 0; m < 4; ++m) {
        #pragma unroll
        for (int j = 0; j < 4; ++j) {
            const int grow = growBase + m * 16 + j;
            const float sa = sA_[m * 4 + j];
            #pragma unroll
            for (int n = 0; n < 4; ++n) {
                const float g   = acc[m][n][j] * sa * sB_[n];
                const float fid = g * g;
                float w = fid >= 0.9f ? 1.0f : (fid >= 0.5f ? 0.5f : 0.0f);
                const int gcol = gcolBase + n * 16;
                if (grow == gcol) w = 0.0f;
                out[(size_t)grow * N + gcol] = w;
            }
        }
    }
}

extern "C" void kernel_launch(void* const* d_in, const int* in_sizes, int n_in,
                              void* d_out, int out_size, void* d_ws, size_t ws_size,
                              hipStream_t stream) {
    const float* features = (const float*)d_in[0];
    float* out = (float*)d_out;
    const int D = 128;
    const int N = in_sizes[0] / D;   // 8192
    dim3 grid(N / 128, N / 128);
    dim3 block(256);
    gram_adj_kernel<<<grid, block, 0, stream>>>(features, out, N);
}

// Round 2
// 79.345 us; speedup vs baseline: 1.4251x; 1.4251x over previous
//
#include <hip/hip_runtime.h>

// GraphAdjacencyLayer: W[i][j] = thresh((fn_i . fn_j)^2), fn = row-normalized features.
// N x 128 fp32 in, N x N fp32 out (N=8192).
//
// Two-kernel plan:
//   K1: fn = f32_normalize(row); store bf16 fn to d_ws (N*128*2 B = 2 MB, L2-resident).
//   K2: Gram via bf16 MFMA, fragments loaded DIRECTLY from global (no LDS, no barrier),
//       threshold + zero-diag epilogue, dword stores. Output 256 MB is the roofline.

typedef __bf16 bf16x8 __attribute__((ext_vector_type(8)));
typedef float f32x4 __attribute__((ext_vector_type(4)));

// ---------------- K1: row-normalize fp32 -> bf16 ----------------------------
// One row per 32 lanes (float4 per lane). 8192 rows * 32 = 262144 threads.
__global__ __launch_bounds__(256)
void norm_cvt_kernel(const float* __restrict__ F, unsigned short* __restrict__ Fb, int N)
{
    const int gtid = blockIdx.x * 256 + threadIdx.x;
    const int row  = gtid >> 5;
    const int c    = gtid & 31;          // float4 column
    if (row >= N) return;

    float4 v = ((const float4*)F)[(size_t)row * 32 + c];
    float ss = v.x * v.x + v.y * v.y + v.z * v.z + v.w * v.w;
    #pragma unroll
    for (int m = 1; m <= 16; m <<= 1) ss += __shfl_xor(ss, m, 64);   // within 32-group
    const float s = 1.0f / (sqrtf(ss) + 1e-12f);

    ushort4 u;
    u.x = __builtin_bit_cast(unsigned short, (__bf16)(v.x * s));
    u.y = __builtin_bit_cast(unsigned short, (__bf16)(v.y * s));
    u.z = __builtin_bit_cast(unsigned short, (__bf16)(v.z * s));
    u.w = __builtin_bit_cast(unsigned short, (__bf16)(v.w * s));
    ((ushort4*)Fb)[(size_t)row * 32 + c] = u;
}

// ---------------- K2: Gram + threshold, no LDS -------------------------------
// 128x128 tile per 256-thread block (4 waves, 2x2 of 64x64). K=128 fully unrolled.
__global__ __launch_bounds__(256, 3)
void gram_thresh_kernel(const unsigned short* __restrict__ Fb, float* __restrict__ out, int N)
{
    const int tid  = threadIdx.x;
    const int lane = tid & 63;
    const int wid  = tid >> 6;
    const int wm   = wid >> 1;
    const int wn   = wid & 1;
    const int fr   = lane & 15;          // fragment row
    const int fkq  = lane >> 4;          // k-quad 0..3

    const int rowTileBase = blockIdx.y * 128;
    const int colTileBase = blockIdx.x * 128;

    // row stride = 128 bf16 = 16 bf16x8 chunks
    const bf16x8* __restrict__ base = (const bf16x8*)Fb;
    const int rowA0 = rowTileBase + wm * 64 + fr;
    const int rowB0 = colTileBase + wn * 64 + fr;

    f32x4 acc[4][4];
    #pragma unroll
    for (int m = 0; m < 4; ++m)
        #pragma unroll
        for (int n = 0; n < 4; ++n)
            acc[m][n] = (f32x4){0.f, 0.f, 0.f, 0.f};

    #pragma unroll
    for (int ks = 0; ks < 4; ++ks) {
        bf16x8 a[4], b[4];
        #pragma unroll
        for (int m = 0; m < 4; ++m)
            a[m] = base[(size_t)(rowA0 + m * 16) * 16 + ks * 4 + fkq];
        #pragma unroll
        for (int n = 0; n < 4; ++n)
            b[n] = base[(size_t)(rowB0 + n * 16) * 16 + ks * 4 + fkq];
        #pragma unroll
        for (int m = 0; m < 4; ++m)
            #pragma unroll
            for (int n = 0; n < 4; ++n)
                acc[m][n] = __builtin_amdgcn_mfma_f32_16x16x32_bf16(a[m], b[n], acc[m][n], 0, 0, 0);
    }

    const int gcolBase = colTileBase + wn * 64 + fr;
    const int growBase = rowTileBase + wm * 64 + fkq * 4;

    #pragma unroll
    for (int m = 0; m < 4; ++m) {
        #pragma unroll
        for (int j = 0; j < 4; ++j) {
            const int grow = growBase + m * 16 + j;
            #pragma unroll
            for (int n = 0; n < 4; ++n) {
                const float g   = acc[m][n][j];
                const float fid = g * g;
                float w = fid >= 0.9f ? 1.0f : (fid >= 0.5f ? 0.5f : 0.0f);
                const int gcol = gcolBase + n * 16;
                if (grow == gcol) w = 0.0f;
                out[(size_t)grow * N + gcol] = w;
            }
        }
    }
}

// ---------------- fallback (round-1 kernel, self-contained) ------------------
__global__ __launch_bounds__(256, 2)
void gram_adj_fused(const float* __restrict__ F, float* __restrict__ out, int N)
{
    __shared__ __align__(16) unsigned short Abf[128 * 128];
    __shared__ __align__(16) unsigned short Bbf[128 * 128];
    __shared__ float scA[128];
    __shared__ float scB[128];

    const int tid  = threadIdx.x;
    const int lane = tid & 63;
    const int wid  = tid >> 6;
    const int wm   = wid >> 1;
    const int wn   = wid & 1;
    const int rowTileBase = blockIdx.y * 128;
    const int colTileBase = blockIdx.x * 128;
    const float4* __restrict__ F4 = (const float4*)F;

    {
        const int c  = tid & 31;
        const int r0 = tid >> 5;
        #pragma unroll 4
        for (int it = 0; it < 16; ++it) {
            const int r = it * 8 + r0;
            float4 va = F4[(size_t)(rowTileBase + r) * 32 + c];
            float4 vb = F4[(size_t)(colTileBase + r) * 32 + c];
            float ssa = va.x * va.x + va.y * va.y + va.z * va.z + va.w * va.w;
            float ssb = vb.x * vb.x + vb.y * vb.y + vb.z * vb.z + vb.w * vb.w;
            #pragma unroll
            for (int m = 1; m <= 16; m <<= 1) {
                ssa += __shfl_xor(ssa, m, 64);
                ssb += __shfl_xor(ssb, m, 64);
            }
            if (c == 0) {
                scA[r] = 1.0f / (sqrtf(ssa) + 1e-12f);
                scB[r] = 1.0f / (sqrtf(ssb) + 1e-12f);
            }
            ushort4 ua, ub;
            ua.x = __builtin_bit_cast(unsigned short, (__bf16)va.x);
            ua.y = __builtin_bit_cast(unsigned short, (__bf16)va.y);
            ua.z = __builtin_bit_cast(unsigned short, (__bf16)va.z);
            ua.w = __builtin_bit_cast(unsigned short, (__bf16)va.w);
            ub.x = __builtin_bit_cast(unsigned short, (__bf16)vb.x);
            ub.y = __builtin_bit_cast(unsigned short, (__bf16)vb.y);
            ub.z = __builtin_bit_cast(unsigned short, (__bf16)vb.z);
            ub.w = __builtin_bit_cast(unsigned short, (__bf16)vb.w);
            const unsigned byte = (unsigned)r * 256u + (unsigned)c * 8u;
            const unsigned swz  = byte ^ ((unsigned)(r & 7) << 4);
            *(ushort4*)((char*)Abf + swz) = ua;
            *(ushort4*)((char*)Bbf + swz) = ub;
        }
    }
    __syncthreads();

    f32x4 acc[4][4];
    #pragma unroll
    for (int m = 0; m < 4; ++m)
        #pragma unroll
        for (int n = 0; n < 4; ++n)
            acc[m][n] = (f32x4){0.f, 0.f, 0.f, 0.f};

    const int fr  = lane & 15;
    const int fkq = lane >> 4;

    #pragma unroll
    for (int ks = 0; ks < 4; ++ks) {
        bf16x8 a[4], b[4];
        #pragma unroll
        for (int m = 0; m < 4; ++m) {
            const int row = wm * 64 + m * 16 + fr;
            const unsigned byte = (unsigned)row * 256u + (unsigned)(ks * 64 + fkq * 16);
            const unsigned swz  = byte ^ ((unsigned)(row & 7) << 4);
            a[m] = *(const bf16x8*)((const char*)Abf + swz);
        }
        #pragma unroll
        for (int n = 0; n < 4; ++n) {
            const int row = wn * 64 + n * 16 + fr;
            const unsigned byte = (unsigned)row * 256u + (unsigned)(ks * 64 + fkq * 16);
            const unsigned swz  = byte ^ ((unsigned)(row & 7) << 4);
            b[n] = *(const bf16x8*)((const char*)Bbf + swz);
        }
        #pragma unroll
        for (int m = 0; m < 4; ++m)
            #pragma unroll
            for (int n = 0; n < 4; ++n)
                acc[m][n] = __builtin_amdgcn_mfma_f32_16x16x32_bf16(a[m], b[n], acc[m][n], 0, 0, 0);
    }

    float sB_[4];
    #pragma unroll
    for (int n = 0; n < 4; ++n) sB_[n] = scB[wn * 64 + n * 16 + fr];
    float sA_[16];
    #pragma unroll
    for (int m = 0; m < 4; ++m)
        #pragma unroll
        for (int j = 0; j < 4; ++j)
            sA_[m * 4 + j] = scA[wm * 64 + m * 16 + fkq * 4 + j];

    const int gcolBase = colTileBase + wn * 64 + fr;
    const int growBase = rowTileBase + wm * 64 + fkq * 4;

    #pragma unroll
    for (int m = 0; m < 4; ++m) {
        #pragma unroll
        for (int j = 0; j < 4; ++j) {
            const int grow = growBase + m * 16 + j;
            const float sa = sA_[m * 4 + j];
            #pragma unroll
            for (int n = 0; n < 4; ++n) {
                const float g   = acc[m][n][j] * sa * sB_[n];
                const float fid = g * g;
                float w = fid >= 0.9f ? 1.0f : (fid >= 0.5f ? 0.5f : 0.0f);
                const int gcol = gcolBase + n * 16;
                if (grow == gcol) w = 0.0f;
                out[(size_t)grow * N + gcol] = w;
            }
        }
    }
}

extern "C" void kernel_launch(void* const* d_in, const int* in_sizes, int n_in,
                              void* d_out, int out_size, void* d_ws, size_t ws_size,
                              hipStream_t stream) {
    const float* features = (const float*)d_in[0];
    float* out = (float*)d_out;
    const int D = 128;
    const int N = in_sizes[0] / D;   // 8192

    const size_t need = (size_t)N * D * sizeof(unsigned short);
    if (ws_size >= need) {
        unsigned short* Fb = (unsigned short*)d_ws;
        const int k1_blocks = (N * 32 + 255) / 256;
        norm_cvt_kernel<<<k1_blocks, 256, 0, stream>>>(features, Fb, N);
        dim3 grid(N / 128, N / 128);
        gram_thresh_kernel<<<grid, dim3(256), 0, stream>>>(Fb, out, N);
    } else {
        dim3 grid(N / 128, N / 128);
        gram_adj_fused<<<grid, dim3(256), 0, stream>>>(features, out, N);
    }
}